// Round 1
// baseline (734.414 us; speedup 1.0000x reference)
//
#include <hip/hip_runtime.h>

// Problem constants (fixed by setup_inputs)
#define NNODES 50000
#define NEDGES 800000
#define MB 8          // B*T
#define CF 32         // in channels
#define OF 32         // out channels
#define FPN 256       // MB*CF floats per node
#define TOTAL_OUT (MB * NNODES * OF)   // 12,800,000

// edge_index may arrive as int32 (harness contract) or int64 (reference dtype).
// flag=1 -> int64 little-endian (read low word at 2*pos), flag=0 -> int32.
__device__ __forceinline__ int ld_idx(const int* p, int pos, int is64) {
    return is64 ? p[2 * pos] : p[pos];
}

__global__ void k_detect(const int* ei, int* flag) {
    int t = threadIdx.x;                 // 64 threads
    int v = ei[2 * t + 1];               // odd words: int64 high words (all 0) vs real indices
    unsigned long long b = __ballot(v != 0);
    if (t == 0) *flag = (b == 0ULL) ? 1 : 0;
}

__global__ void k_deg_hist(const int* ei, const float* w, const int* flag,
                           float* deg, int* counts) {
    int e = blockIdx.x * blockDim.x + threadIdx.x;
    if (e >= NEDGES) return;
    int is64 = *flag;
    int s = ld_idx(ei, e, is64);
    int d = ld_idx(ei, NEDGES + e, is64);
    atomicAdd(&deg[s], w[e]);
    atomicAdd(&counts[d], 1);
}

__global__ void k_dinv(float* deg) {
    int n = blockIdx.x * blockDim.x + threadIdx.x;
    if (n >= NNODES) return;
    float dg = deg[n];
    deg[n] = (dg > 0.0f) ? (1.0f / sqrtf(dg)) : 0.0f;   // in-place: deg -> dinv
}

__global__ void __launch_bounds__(1024) k_scan(const int* counts, int* row_ptr, int* write_ptr) {
    __shared__ int sdata[1024];
    __shared__ int s_base;
    int t = threadIdx.x;
    if (t == 0) { s_base = 0; row_ptr[0] = 0; }
    __syncthreads();
    for (int start = 0; start < NNODES; start += 1024) {
        int i = start + t;
        int c = (i < NNODES) ? counts[i] : 0;
        sdata[t] = c;
        __syncthreads();
        for (int off = 1; off < 1024; off <<= 1) {
            int v = (t >= off) ? sdata[t - off] : 0;
            __syncthreads();
            sdata[t] += v;
            __syncthreads();
        }
        int incl = sdata[t];
        int base = s_base;
        __syncthreads();
        if (i < NNODES) {
            row_ptr[i + 1]  = base + incl;
            write_ptr[i]    = base + incl - c;
        }
        if (t == 1023) s_base = base + incl;
        __syncthreads();
    }
}

__global__ void k_scatter(const int* ei, const float* w, const int* flag,
                          const float* dinv, int* write_ptr, int* col, float* val) {
    int e = blockIdx.x * blockDim.x + threadIdx.x;
    if (e >= NEDGES) return;
    int is64 = *flag;
    int s = ld_idx(ei, e, is64);
    int d = ld_idx(ei, NEDGES + e, is64);
    float nv = -dinv[s] * w[e] * dinv[d];
    int pos = atomicAdd(&write_ptr[d], 1);
    col[pos] = s;
    val[pos] = nv;
}

// Transpose x -> xn [n][m][c], and out = xn*W0 + bias written to d_out [m][n][o]
__global__ void __launch_bounds__(256) k_prep(const float* x, const float* W, const float* bias,
                                              float* xn, float* out) {
    int n = blockIdx.x;
    int t = threadIdx.x;
    int m = t >> 5, c = t & 31;
    __shared__ float sT[FPN];
    __shared__ float sW[CF * OF];
    for (int i = t; i < CF * OF; i += 256) sW[i] = W[i];          // W[0]
    float xv = x[(m * NNODES + n) * CF + c];
    sT[t] = xv;
    xn[n * FPN + t] = xv;
    __syncthreads();
    int o = c;
    float acc = bias[o];
    #pragma unroll
    for (int cc = 0; cc < CF; cc++)
        acc += sT[m * CF + cc] * sW[cc * OF + o];
    out[(m * NNODES + n) * OF + o] = acc;
}

// PHASE 1: t1 = lap(xn); out += t1*W1  (stores t1)
// PHASE 2: t2 = 2*lap(t1) - xn; out += t2*W2  (t2 not stored)
template <int PHASE>
__global__ void __launch_bounds__(256) k_spmm(const float* src_feat, const float* xn0,
                                              const float* W,
                                              const int* row_ptr, const int* col,
                                              const float* val,
                                              float* t_store, float* out) {
    int n = blockIdx.x;
    int t = threadIdx.x;
    __shared__ float sW[CF * OF];
    __shared__ float sT[FPN];
    __shared__ int   sCol[256];
    __shared__ float sVal[256];
    const float* Wk = W + (PHASE == 1 ? CF * OF : 2 * CF * OF);
    for (int i = t; i < CF * OF; i += 256) sW[i] = Wk[i];
    int rs = row_ptr[n], re = row_ptr[n + 1];
    float acc = 0.0f;
    for (int base = rs; base < re; base += 256) {
        __syncthreads();
        int j = base + t;
        if (j < re) { sCol[t] = col[j]; sVal[t] = val[j]; }
        __syncthreads();
        int cnt = min(256, re - base);
        for (int k = 0; k < cnt; k++)
            acc += sVal[k] * src_feat[sCol[k] * FPN + t];
    }
    float tv;
    if (PHASE == 1) {
        tv = acc;
        t_store[n * FPN + t] = tv;
    } else {
        tv = 2.0f * acc - xn0[n * FPN + t];
    }
    __syncthreads();
    sT[t] = tv;
    __syncthreads();
    int m = t >> 5, o = t & 31;
    float s = 0.0f;
    #pragma unroll
    for (int c = 0; c < CF; c++)
        s += sT[m * CF + c] * sW[c * OF + o];
    out[(m * NNODES + n) * OF + o] += s;
}

// BN stats: sum and sumsq over nodes per (m,o)
__global__ void __launch_bounds__(256) k_stats(const float* out, float* stats) {
    int m = blockIdx.y;
    int t = threadIdx.x;
    int o = t & 31, r = t >> 5;
    int n0 = blockIdx.x * 1024;
    int nend = min(n0 + 1024, NNODES);
    float s = 0.0f, q = 0.0f;
    for (int n = n0 + r; n < nend; n += 8) {
        float v = out[(m * NNODES + n) * OF + o];
        s += v; q += v * v;
    }
    __shared__ float sS[256];
    __shared__ float sQ[256];
    sS[t] = s; sQ[t] = q;
    __syncthreads();
    for (int off = 128; off >= 32; off >>= 1) {
        if (t < off) { sS[t] += sS[t + off]; sQ[t] += sQ[t + off]; }
        __syncthreads();
    }
    if (t < 32) {
        atomicAdd(&stats[m * 32 + t], sS[t]);
        atomicAdd(&stats[256 + m * 32 + t], sQ[t]);
    }
}

__global__ void k_bnprep(const float* stats, const float* gamma, const float* beta,
                         float* scale, float* shift) {
    int i = threadIdx.x;   // 256 = MB*OF
    float mean = stats[i] / (float)NNODES;
    float var  = stats[256 + i] / (float)NNODES - mean * mean;
    float inv  = 1.0f / sqrtf(var + 1e-5f);
    int o = i & 31;
    float sc = gamma[o] * inv;
    scale[i] = sc;
    shift[i] = beta[o] - sc * mean;
}

__global__ void k_final(float* out, const float* scale, const float* shift) {
    int idx = blockIdx.x * blockDim.x + threadIdx.x;
    if (idx >= TOTAL_OUT) return;
    int o = idx & 31;
    int m = idx / (NNODES * OF);
    int mo = m * 32 + o;
    float v = out[idx] * scale[mo] + shift[mo];
    out[idx] = fmaxf(v, 0.0f);
}

extern "C" void kernel_launch(void* const* d_in, const int* in_sizes, int n_in,
                              void* d_out, int out_size, void* d_ws, size_t ws_size,
                              hipStream_t stream) {
    const float* x     = (const float*)d_in[0];
    const int*   ei    = (const int*)d_in[1];
    const float* w     = (const float*)d_in[2];
    const float* W     = (const float*)d_in[3];
    const float* bias  = (const float*)d_in[4];
    const float* gamma = (const float*)d_in[5];
    const float* beta  = (const float*)d_in[6];
    float* out = (float*)d_out;

    char* p = (char*)d_ws;
    auto alloc = [&](size_t bytes) {
        char* r = p;
        p += (bytes + 511) & ~(size_t)511;
        return r;
    };
    int*   flag      = (int*)alloc(4);
    float* deg       = (float*)alloc((size_t)NNODES * 4);       // becomes dinv in place
    int*   counts    = (int*)alloc((size_t)NNODES * 4);
    float* stats     = (float*)alloc(512 * 4);
    int*   row_ptr   = (int*)alloc((size_t)(NNODES + 1) * 4);
    int*   write_ptr = (int*)alloc((size_t)NNODES * 4);
    int*   col       = (int*)alloc((size_t)NEDGES * 4);
    float* val       = (float*)alloc((size_t)NEDGES * 4);
    float* scale     = (float*)alloc(256 * 4);
    float* shift     = (float*)alloc(256 * 4);
    float* xn        = (float*)alloc((size_t)NNODES * FPN * 4);
    float* t1        = (float*)alloc((size_t)NNODES * FPN * 4);

    // zero deg..stats (contiguous in layout, padding included)
    size_t zlen = (char*)(stats + 512) - (char*)deg;
    hipMemsetAsync(deg, 0, zlen, stream);

    k_detect<<<1, 64, 0, stream>>>(ei, flag);

    int eblocks = (NEDGES + 255) / 256;
    int nblocks = (NNODES + 255) / 256;
    k_deg_hist<<<eblocks, 256, 0, stream>>>(ei, w, flag, deg, counts);
    k_dinv<<<nblocks, 256, 0, stream>>>(deg);
    k_scan<<<1, 1024, 0, stream>>>(counts, row_ptr, write_ptr);
    k_scatter<<<eblocks, 256, 0, stream>>>(ei, w, flag, deg, write_ptr, col, val);

    k_prep<<<NNODES, 256, 0, stream>>>(x, W, bias, xn, out);
    k_spmm<1><<<NNODES, 256, 0, stream>>>(xn, xn, W, row_ptr, col, val, t1, out);
    k_spmm<2><<<NNODES, 256, 0, stream>>>(t1, xn, W, row_ptr, col, val, t1, out);

    dim3 sgrid((NNODES + 1023) / 1024, MB);
    k_stats<<<sgrid, 256, 0, stream>>>(out, stats);
    k_bnprep<<<1, 256, 0, stream>>>(stats, gamma, beta, scale, shift);
    k_final<<<(TOTAL_OUT + 255) / 256, 256, 0, stream>>>(out, scale, shift);
}